// Round 9
// baseline (36.261 us; speedup 1.0000x reference)
//
#include <hip/hip_runtime.h>

// y[b,o,h,w] = sum_j alphas[o,j] * x[b,j,(128-h)&127,(128-w)&127]
// (FFT2 -> complex channel mix -> IFFT2 collapses to flipped-input channel GEMM;
//  betas contributes only to the imaginary part and drops out.)
//
// Barrier-free streaming (round-7/8 structure, verified) + DEPTH-4 prefetch:
//  - each wave owns (b, h, 16-wide w-chunk), computes all 128 o channels
//  - A-frags from a 32KB swizzled alphas LDS (staged ONCE per block)
//  - B-frags via scalar global loads; FOUR k-groups (32 loads, 8KB/wave) in
//    flight: tile A fully issued in prologue, tile B's group s+4 issued while
//    consuming group s -> >=600cy lead per consume, covers L3/HBM latency.
//  - all tile-B loads issue BEFORE any tile-A store (no store-vmcnt coupling)
//  - persistent blocks: grid 512 = residency capacity, 2 tiles/block.

using bf16   = __bf16;
using bf16x8 = __attribute__((ext_vector_type(8))) __bf16;
using f32x4  = __attribute__((ext_vector_type(4))) float;

// alphas LDS: bf16 [o][k], 256 B rows, 16B-granule XOR swizzle:
//   byte(o,k) = o*256 + (k*2 ^ ((o&7)<<4))
// Frag reads (o=mf*16+lr, k0=ks*32+g*8) hit each bank-quad with exactly 8
// lanes (conflict-free floor); staging writes likewise uniform. (Verified r7/8.)
static __device__ __forceinline__ int aoff(int o, int k) {
    return o * 256 + ((k * 2) ^ ((o & 7) << 4));
}

__global__ __launch_bounds__(512, 4)
void kk_freqmix_kernel(const float* __restrict__ x,
                       const float* __restrict__ alphas,
                       float* __restrict__ out)
{
    __shared__ unsigned char ldsA[32768];

    const int t   = threadIdx.x;        // 0..511
    const int bid = blockIdx.x;         // 0..511 (persistent, 2 tiles each)

    const int l  = t & 63;
    const int wc = t >> 6;              // wave 0..7 owns w-chunk [wc*16, +16)
    const int g  = l >> 4;              // k-slice selector
    const int lr = l & 15;
    const int w  = wc * 16 + lr;        // output column this lane produces
    const int ws = (128 - w) & 127;     // source column (w-flip at load)

    // Two consecutive tiles; tA even -> both share batch bb.
    const int tA  = bid * 2;
    const int bb  = tA >> 7;
    const int hA  = tA & 127,          hB  = (tA + 1) & 127;
    const int hsA = (128 - hA) & 127,  hsB = (128 - hB) & 127;

    const float* xcol[2] = {
        x + (size_t)bb * 2097152 + (size_t)hsA * 128 + ws,
        x + (size_t)bb * 2097152 + (size_t)hsB * 128 + ws };
    float* const outp[2] = {
        out + (size_t)bb * 2097152 + (size_t)hA * 128 + w,
        out + (size_t)bb * 2097152 + (size_t)hB * 128 + w };

    // ---- pipeline prologue: issue ALL of tile A (groups 0..3, 32 loads) ----
    float xv[4][8];
    #pragma unroll
    for (int s = 0; s < 4; ++s)
        #pragma unroll
        for (int v = 0; v < 8; ++v)
            xv[s][v] = xcol[0][(s * 32 + g * 8 + v) * 16384];

    // ---- stage alphas (64KB fp32 -> 32KB bf16 LDS), once per block ----
    {
        const int o   = t >> 2;         // 0..127
        const int seg = t & 3;          // 32-wide k segment
        const float* ap = alphas + o * 128 + seg * 32;
        #pragma unroll
        for (int j = 0; j < 4; ++j) {
            const float4 a0 = *(const float4*)(ap + j * 8);
            const float4 a1 = *(const float4*)(ap + j * 8 + 4);
            bf16x8 vv;
            vv[0]=(bf16)a0.x; vv[1]=(bf16)a0.y; vv[2]=(bf16)a0.z; vv[3]=(bf16)a0.w;
            vv[4]=(bf16)a1.x; vv[5]=(bf16)a1.y; vv[6]=(bf16)a1.z; vv[7]=(bf16)a1.w;
            *(bf16x8*)(ldsA + aoff(o, seg * 32 + j * 8)) = vv;
        }
    }
    __syncthreads();   // the ONLY barrier; tile-A load latency hid under staging

    // ---- persistent tile loop, fully unrolled (all xv indices static) ----
    f32x4 acc[8];
    #pragma unroll
    for (int tl = 0; tl < 2; ++tl) {
        #pragma unroll
        for (int mf = 0; mf < 8; ++mf) acc[mf] = (f32x4){0.f, 0.f, 0.f, 0.f};

        #pragma unroll
        for (int ks = 0; ks < 4; ++ks) {
            const int s   = tl * 4 + ks;    // global pipeline step 0..7
            const int buf = s & 3;
            // consume buffer (data for step s); first use forces vmcnt wait
            bf16x8 bfrag;
            #pragma unroll
            for (int v = 0; v < 8; ++v) bfrag[v] = (bf16)xv[buf][v];
            // refill: during tile A, issue tile B's group ks into freed buffer
            if (tl == 0) {
                #pragma unroll
                for (int v = 0; v < 8; ++v)
                    xv[buf][v] = xcol[1][(ks * 32 + g * 8 + v) * 16384];
            }
            const int k0 = ks * 32 + g * 8;  // sigma(g,v)=g*8+v on A and B
            #pragma unroll
            for (int mf = 0; mf < 8; ++mf) {
                const bf16x8 afrag = *(const bf16x8*)(ldsA + aoff(mf * 16 + lr, k0));
                acc[mf] = __builtin_amdgcn_mfma_f32_16x16x32_bf16(afrag, bfrag, acc[mf], 0, 0, 0);
            }
        }

        // ---- stores: D col(w)=lane&15, row(o)=g*4+r (verified layout) ----
        // 16 lanes x 4B contiguous per (mf,r); all tile-B loads already issued,
        // so these stores never gate a later load's vmcnt wait.
        #pragma unroll
        for (int mf = 0; mf < 8; ++mf) {
            #pragma unroll
            for (int r = 0; r < 4; ++r)
                outp[tl][(size_t)(mf * 16 + g * 4 + r) * 16384] = acc[mf][r];
        }
    }
}

extern "C" void kernel_launch(void* const* d_in, const int* in_sizes, int n_in,
                              void* d_out, int out_size, void* d_ws, size_t ws_size,
                              hipStream_t stream) {
    const float* x      = (const float*)d_in[0];
    const float* alphas = (const float*)d_in[1];
    // betas (d_in[2]) provably unused: contributes only to Im(y), dropped by real().
    float* out = (float*)d_out;

    dim3 grid(512);    // persistent: exactly 2 blocks/CU, 2 tiles per block
    dim3 block(512);
    hipLaunchKernelGGL(kk_freqmix_kernel, grid, block, 0, stream, x, alphas, out);
}

// Round 10
// 32.370 us; speedup vs baseline: 1.1202x; 1.1202x over previous
//
#include <hip/hip_runtime.h>

// y[b,o,h,w] = sum_j alphas[o,j] * x[b,j,(128-h)&127,(128-w)&127]
// (FFT2 -> complex channel mix -> IFFT2 collapses to flipped-input channel GEMM;
//  betas contributes only to the imaginary part and drops out.)
//
// Round-8 skeleton (28.3us, proven): persistent grid 512, 2 tiles/block,
// single alphas-LDS barrier, depth-2 parity prefetch, flip-at-load.
// NEW: 32x32x16 MFMA tiles so every global load AND store instruction covers
// full 128B cache lines (fix for the measured ~30% HBM write amplification
// of the 16x16 layout's 64B row-segments).
//   D[o][w] = sum_k alphas[o][k] * X[k][w]
//   wave wv: ow=wv>>2 picks o-half (2 32-tiles), wc=wv&3 picks 32-wide w-chunk
//   C/D (m74/m101-verified): col=lane&31, row=(reg&3)+8*(reg>>2)+4*(lane>>5)
//   A/B k-slots: k = k0 + (lane>>5)*8 + v on BOTH operands (self-consistent).

using bf16   = __bf16;
using bf16x8 = __attribute__((ext_vector_type(8))) __bf16;
using f32x16 = __attribute__((ext_vector_type(16))) float;

// alphas LDS: bf16 [o][k], 256 B rows, 16B-granule XOR swizzle:
//   byte(o,k) = o*256 + (k*2 ^ ((o&7)<<4))
// 32x32 A-frag read (o=ot*32+c, k-granule k0+hi*8): byte bits 4-6 =
// kbits ^ (o&7) ^ (hi<<0 shift) -> every 16B bank-group serves exactly 8
// lanes = balanced b128 floor. Staging writes unchanged from r7/8 (balanced).
static __device__ __forceinline__ int aoff(int o, int k) {
    return o * 256 + ((k * 2) ^ ((o & 7) << 4));
}

__global__ __launch_bounds__(512, 4)
void kk_freqmix_kernel(const float* __restrict__ x,
                       const float* __restrict__ alphas,
                       float* __restrict__ out)
{
    __shared__ unsigned char ldsA[32768];

    const int t   = threadIdx.x;        // 0..511
    const int bid = blockIdx.x;         // 0..511 (persistent, 2 tiles each)

    const int l  = t & 63;
    const int wv = t >> 6;              // wave 0..7
    const int ow = wv >> 2;             // o-half: tiles {ow*2, ow*2+1}
    const int wc = wv & 3;              // w-chunk [wc*32, +32)
    const int c  = l & 31;              // column within chunk
    const int hi = l >> 5;              // k-half selector
    const int w  = wc * 32 + c;         // output column this lane produces
    const int ws = (128 - w) & 127;     // source column (w-flip at load)

    // Two consecutive tiles; tA even -> both share batch bb.
    const int tA  = bid * 2;
    const int bb  = tA >> 7;
    const int hA  = tA & 127,          hB  = (tA + 1) & 127;
    const int hsA = (128 - hA) & 127,  hsB = (128 - hB) & 127;

    const float* xcol[2] = {
        x + (size_t)bb * 2097152 + (size_t)hsA * 128 + ws,
        x + (size_t)bb * 2097152 + (size_t)hsB * 128 + ws };
    float* const outp[2] = {
        out + (size_t)bb * 2097152 + (size_t)hA * 128 + w,
        out + (size_t)bb * 2097152 + (size_t)hB * 128 + w };

    // ---- prologue: issue k-steps 0,1 of tile A (16 loads, r8-proven depth) ----
    // Per instruction: hi=0 lanes cover 128B of row k0+v, hi=1 of row k0+8+v.
    float xv[2][8];
    #pragma unroll
    for (int v = 0; v < 8; ++v) xv[0][v] = xcol[0][(     hi * 8 + v) * 16384];
    #pragma unroll
    for (int v = 0; v < 8; ++v) xv[1][v] = xcol[0][(16 + hi * 8 + v) * 16384];

    // ---- stage alphas (64KB fp32 -> 32KB bf16 LDS), once per block ----
    {
        const int o   = t >> 2;         // 0..127
        const int seg = t & 3;          // 32-wide k segment
        const float* ap = alphas + o * 128 + seg * 32;
        #pragma unroll
        for (int j = 0; j < 4; ++j) {
            const float4 a0 = *(const float4*)(ap + j * 8);
            const float4 a1 = *(const float4*)(ap + j * 8 + 4);
            bf16x8 vv;
            vv[0]=(bf16)a0.x; vv[1]=(bf16)a0.y; vv[2]=(bf16)a0.z; vv[3]=(bf16)a0.w;
            vv[4]=(bf16)a1.x; vv[5]=(bf16)a1.y; vv[6]=(bf16)a1.z; vv[7]=(bf16)a1.w;
            *(bf16x8*)(ldsA + aoff(o, seg * 32 + j * 8)) = vv;
        }
    }
    __syncthreads();   // the ONLY barrier; steps 0,1 latency hid under staging

    // ---- persistent tile loop, fully unrolled (all indices static) ----
    f32x16 acc[2];
    #pragma unroll
    for (int tl = 0; tl < 2; ++tl) {
        #pragma unroll
        for (int nt = 0; nt < 2; ++nt)
            #pragma unroll
            for (int r = 0; r < 16; ++r) acc[nt][r] = 0.f;

        #pragma unroll
        for (int st = 0; st < 8; ++st) {      // 8 k-steps of 16 (32x32x16)
            const int s   = tl * 8 + st;      // global pipeline step 0..15
            const int buf = s & 1;
            // consume buffer (B-frag: X[k0+hi*8+v][w])
            bf16x8 bfrag;
            #pragma unroll
            for (int v = 0; v < 8; ++v) bfrag[v] = (bf16)xv[buf][v];
            // refill: issue step s+2 into the freed buffer (r8-proven schedule)
            if (s + 2 < 16) {
                const int tl2 = (s + 2) >> 3, st2 = (s + 2) & 7;
                #pragma unroll
                for (int v = 0; v < 8; ++v)
                    xv[buf][v] = xcol[tl2][(st2 * 16 + hi * 8 + v) * 16384];
            }
            const int k0 = st * 16;
            #pragma unroll
            for (int nt = 0; nt < 2; ++nt) {
                const int o_l = (ow * 2 + nt) * 32 + c;   // A row this lane feeds
                const bf16x8 afrag = *(const bf16x8*)(ldsA + aoff(o_l, k0 + hi * 8));
                acc[nt] = __builtin_amdgcn_mfma_f32_32x32x16_bf16(afrag, bfrag, acc[nt], 0, 0, 0);
            }
        }

        // ---- stores: col(w)=lane&31 -> 32 lanes x 4B = full 128B line per
        // hi-half; each instruction writes exactly 2 full lines. ----
        #pragma unroll
        for (int nt = 0; nt < 2; ++nt) {
            const int o_base = (ow * 2 + nt) * 32 + hi * 4;
            #pragma unroll
            for (int r = 0; r < 16; ++r) {
                const int o = o_base + (r & 3) + 8 * (r >> 2);
                outp[tl][(size_t)o * 16384] = acc[nt][r];
            }
        }
    }
}

extern "C" void kernel_launch(void* const* d_in, const int* in_sizes, int n_in,
                              void* d_out, int out_size, void* d_ws, size_t ws_size,
                              hipStream_t stream) {
    const float* x      = (const float*)d_in[0];
    const float* alphas = (const float*)d_in[1];
    // betas (d_in[2]) provably unused: contributes only to Im(y), dropped by real().
    float* out = (float*)d_out;

    dim3 grid(512);    // persistent: exactly 2 blocks/CU, 2 tiles per block
    dim3 block(512);
    hipLaunchKernelGGL(kk_freqmix_kernel, grid, block, 0, stream, x, alphas, out);
}

// Round 11
// 28.086 us; speedup vs baseline: 1.2910x; 1.1525x over previous
//
#include <hip/hip_runtime.h>

// y[b,o,h,w] = sum_j alphas[o,j] * x[b,j,(128-h)&127,(128-w)&127]
// (FFT2 -> complex channel mix -> IFFT2 collapses to flipped-input channel GEMM;
//  betas contributes only to the imaginary part and drops out.)
//
// 32x32x16 MFMA, full-128B-line loads AND stores (r10-verified layout), with
// r10's two defects fixed:
//  - amdgpu_waves_per_eu(4,4): pins 128-VGPR budget, stops the backend from
//    squeezing to 64 VGPR and sinking the prefetch loads (r9/r10 regression).
//  - no duplicate x loads: block = 2 h-rows, wave = (h-row, 32-wide w-chunk);
//    each wave computes ALL 128 o (4 acc tiles, 64 VGPR) for its columns.
// Skeleton otherwise r8-proven: single alphas-LDS barrier, depth-2 parity
// prefetch (16 loads in flight), flip-at-load, grid 512 single pass.
//
//   D[o][w] = sum_k alphas[o][k] * X[k][w]
//   C/D (m74/m101 + r10-verified): col=lane&31, row=(reg&3)+8*(reg>>2)+4*(lane>>5)
//   A/B k-slots: k = k0 + (lane>>5)*8 + v on BOTH operands (self-consistent).

using bf16   = __bf16;
using bf16x8 = __attribute__((ext_vector_type(8))) __bf16;
using f32x16 = __attribute__((ext_vector_type(16))) float;

// alphas LDS: bf16 [o][k], 256 B rows, 16B-granule XOR swizzle:
//   byte(o,k) = o*256 + (k*2 ^ ((o&7)<<4))   (r7/r8/r10-verified)
static __device__ __forceinline__ int aoff(int o, int k) {
    return o * 256 + ((k * 2) ^ ((o & 7) << 4));
}

__global__ __launch_bounds__(512)
__attribute__((amdgpu_waves_per_eu(4, 4)))
void kk_freqmix_kernel(const float* __restrict__ x,
                       const float* __restrict__ alphas,
                       float* __restrict__ out)
{
    __shared__ unsigned char ldsA[32768];

    const int t   = threadIdx.x;        // 0..511
    const int bid = blockIdx.x;         // 0..511, covers 2 h-rows

    const int l   = t & 63;
    const int wv  = t >> 6;             // wave 0..7
    const int hsl = wv >> 2;            // h-row selector within block
    const int wc  = wv & 3;             // w-chunk [wc*32, +32)
    const int c   = l & 31;             // column within chunk
    const int hi  = l >> 5;             // k-half selector
    const int w   = wc * 32 + c;        // output column this lane produces
    const int ws  = (128 - w) & 127;    // source column (w-flip at load)

    const int tile = bid * 2 + hsl;     // 0..1023 (both tiles share batch)
    const int b    = tile >> 7;
    const int h    = tile & 127;
    const int hs   = (128 - h) & 127;   // source row (h-flip)

    const float* xcol = x   + (size_t)b * 2097152 + (size_t)hs * 128 + ws;
    float* const op   = out + (size_t)b * 2097152 + (size_t)h  * 128 + w;

    // ---- prologue: issue k-steps 0,1 (16 loads; r8-proven depth 2) ----
    // Per instruction: 32 lanes x 4B contiguous per hi-half = full 128B lines.
    float xv[2][8];
    #pragma unroll
    for (int v = 0; v < 8; ++v) xv[0][v] = xcol[(     hi * 8 + v) * 16384];
    #pragma unroll
    for (int v = 0; v < 8; ++v) xv[1][v] = xcol[(16 + hi * 8 + v) * 16384];

    // ---- stage alphas (64KB fp32 -> 32KB bf16 LDS), once per block ----
    {
        const int o   = t >> 2;         // 0..127
        const int seg = t & 3;          // 32-wide k segment
        const float* ap = alphas + o * 128 + seg * 32;
        #pragma unroll
        for (int j = 0; j < 4; ++j) {
            const float4 a0 = *(const float4*)(ap + j * 8);
            const float4 a1 = *(const float4*)(ap + j * 8 + 4);
            bf16x8 vv;
            vv[0]=(bf16)a0.x; vv[1]=(bf16)a0.y; vv[2]=(bf16)a0.z; vv[3]=(bf16)a0.w;
            vv[4]=(bf16)a1.x; vv[5]=(bf16)a1.y; vv[6]=(bf16)a1.z; vv[7]=(bf16)a1.w;
            *(bf16x8*)(ldsA + aoff(o, seg * 32 + j * 8)) = vv;
        }
    }
    __syncthreads();   // the ONLY barrier; steps 0,1 latency hid under staging

    // ---- k-loop: 8 steps of 16, depth-2 parity prefetch ----
    f32x16 acc[4];     // o-tiles 0..3 (o = nt*32 + ...)
    #pragma unroll
    for (int nt = 0; nt < 4; ++nt)
        #pragma unroll
        for (int r = 0; r < 16; ++r) acc[nt][r] = 0.f;

    #pragma unroll
    for (int st = 0; st < 8; ++st) {
        const int buf = st & 1;
        // consume (B-frag: X[k0 + hi*8 + v][w])
        bf16x8 bfrag;
        #pragma unroll
        for (int v = 0; v < 8; ++v) bfrag[v] = (bf16)xv[buf][v];
        // refill: issue step st+2 into the freed buffer
        if (st + 2 < 8) {
            #pragma unroll
            for (int v = 0; v < 8; ++v)
                xv[buf][v] = xcol[((st + 2) * 16 + hi * 8 + v) * 16384];
        }
        const int k0 = st * 16;
        #pragma unroll
        for (int nt = 0; nt < 4; ++nt) {
            const int o_l = nt * 32 + c;            // A row this lane feeds
            const bf16x8 afrag = *(const bf16x8*)(ldsA + aoff(o_l, k0 + hi * 8));
            acc[nt] = __builtin_amdgcn_mfma_f32_32x32x16_bf16(afrag, bfrag, acc[nt], 0, 0, 0);
        }
    }

    // ---- stores: col(w)=lane&31 -> each instruction writes 2 full 128B lines
    // (hi=0/1 halves hit adjacent o-rows). ----
    #pragma unroll
    for (int nt = 0; nt < 4; ++nt) {
        const int o_base = nt * 32 + hi * 4;
        #pragma unroll
        for (int r = 0; r < 16; ++r) {
            const int o = o_base + (r & 3) + 8 * (r >> 2);
            op[(size_t)o * 16384] = acc[nt][r];
        }
    }
}

extern "C" void kernel_launch(void* const* d_in, const int* in_sizes, int n_in,
                              void* d_out, int out_size, void* d_ws, size_t ws_size,
                              hipStream_t stream) {
    const float* x      = (const float*)d_in[0];
    const float* alphas = (const float*)d_in[1];
    // betas (d_in[2]) provably unused: contributes only to Im(y), dropped by real().
    float* out = (float*)d_out;

    dim3 grid(512);    // 2 h-rows per block: 512 * 2 = 1024 tiles
    dim3 block(512);
    hipLaunchKernelGGL(kk_freqmix_kernel, grid, block, 0, stream, x, alphas, out);
}

// Round 12
// 27.802 us; speedup vs baseline: 1.3042x; 1.0102x over previous
//
#include <hip/hip_runtime.h>

// y[b,o,h,w] = sum_j alphas[o,j] * x[b,j,(128-h)&127,(128-w)&127]
// (FFT2 -> complex channel mix -> IFFT2 collapses to flipped-input channel GEMM;
//  betas contributes only to the imaginary part and drops out.)
//
// Round-11 kernel (28.09us, best) with ONE change: nontemporal full-line
// stores. r11's plain stores stream 64MiB through L3 every replay, evicting
// ~half of the L3-resident x (measured FETCH 40MB vs 64MiB read set). nt
// stores keep L3 for the read stream. (r2's anti-nt evidence was confounded
// by its 16x16 half-line stores -- r9 plain/half-line: 87MB write vs
// r10/r11 full-line: 71MB.)
//
//   D[o][w] = sum_k alphas[o][k] * X[k][w]
//   C/D (m74/m101 + r10/r11-verified): col=lane&31, row=(reg&3)+8*(reg>>2)+4*(lane>>5)
//   A/B k-slots: k = k0 + (lane>>5)*8 + v on BOTH operands (self-consistent).

using bf16   = __bf16;
using bf16x8 = __attribute__((ext_vector_type(8))) __bf16;
using f32x16 = __attribute__((ext_vector_type(16))) float;

// alphas LDS: bf16 [o][k], 256 B rows, 16B-granule XOR swizzle:
//   byte(o,k) = o*256 + (k*2 ^ ((o&7)<<4))   (r7/r8/r10/r11-verified)
static __device__ __forceinline__ int aoff(int o, int k) {
    return o * 256 + ((k * 2) ^ ((o & 7) << 4));
}

__global__ __launch_bounds__(512)
__attribute__((amdgpu_waves_per_eu(4, 4)))
void kk_freqmix_kernel(const float* __restrict__ x,
                       const float* __restrict__ alphas,
                       float* __restrict__ out)
{
    __shared__ unsigned char ldsA[32768];

    const int t   = threadIdx.x;        // 0..511
    const int bid = blockIdx.x;         // 0..511, covers 2 h-rows

    const int l   = t & 63;
    const int wv  = t >> 6;             // wave 0..7
    const int hsl = wv >> 2;            // h-row selector within block
    const int wc  = wv & 3;             // w-chunk [wc*32, +32)
    const int c   = l & 31;             // column within chunk
    const int hi  = l >> 5;             // k-half selector
    const int w   = wc * 32 + c;        // output column this lane produces
    const int ws  = (128 - w) & 127;    // source column (w-flip at load)

    const int tile = bid * 2 + hsl;     // 0..1023 (both tiles share batch)
    const int b    = tile >> 7;
    const int h    = tile & 127;
    const int hs   = (128 - h) & 127;   // source row (h-flip)

    const float* xcol = x   + (size_t)b * 2097152 + (size_t)hs * 128 + ws;
    float* const op   = out + (size_t)b * 2097152 + (size_t)h  * 128 + w;

    // ---- prologue: issue k-steps 0,1 (16 loads; r8-proven depth 2) ----
    // Per instruction: 32 lanes x 4B contiguous per hi-half = full 128B lines.
    float xv[2][8];
    #pragma unroll
    for (int v = 0; v < 8; ++v) xv[0][v] = xcol[(     hi * 8 + v) * 16384];
    #pragma unroll
    for (int v = 0; v < 8; ++v) xv[1][v] = xcol[(16 + hi * 8 + v) * 16384];

    // ---- stage alphas (64KB fp32 -> 32KB bf16 LDS), once per block ----
    {
        const int o   = t >> 2;         // 0..127
        const int seg = t & 3;          // 32-wide k segment
        const float* ap = alphas + o * 128 + seg * 32;
        #pragma unroll
        for (int j = 0; j < 4; ++j) {
            const float4 a0 = *(const float4*)(ap + j * 8);
            const float4 a1 = *(const float4*)(ap + j * 8 + 4);
            bf16x8 vv;
            vv[0]=(bf16)a0.x; vv[1]=(bf16)a0.y; vv[2]=(bf16)a0.z; vv[3]=(bf16)a0.w;
            vv[4]=(bf16)a1.x; vv[5]=(bf16)a1.y; vv[6]=(bf16)a1.z; vv[7]=(bf16)a1.w;
            *(bf16x8*)(ldsA + aoff(o, seg * 32 + j * 8)) = vv;
        }
    }
    __syncthreads();   // the ONLY barrier; steps 0,1 latency hid under staging

    // ---- k-loop: 8 steps of 16, depth-2 parity prefetch ----
    f32x16 acc[4];     // o-tiles 0..3 (o = nt*32 + ...)
    #pragma unroll
    for (int nt = 0; nt < 4; ++nt)
        #pragma unroll
        for (int r = 0; r < 16; ++r) acc[nt][r] = 0.f;

    #pragma unroll
    for (int st = 0; st < 8; ++st) {
        const int buf = st & 1;
        // consume (B-frag: X[k0 + hi*8 + v][w])
        bf16x8 bfrag;
        #pragma unroll
        for (int v = 0; v < 8; ++v) bfrag[v] = (bf16)xv[buf][v];
        // refill: issue step st+2 into the freed buffer
        if (st + 2 < 8) {
            #pragma unroll
            for (int v = 0; v < 8; ++v)
                xv[buf][v] = xcol[((st + 2) * 16 + hi * 8 + v) * 16384];
        }
        const int k0 = st * 16;
        #pragma unroll
        for (int nt = 0; nt < 4; ++nt) {
            const int o_l = nt * 32 + c;            // A row this lane feeds
            const bf16x8 afrag = *(const bf16x8*)(ldsA + aoff(o_l, k0 + hi * 8));
            acc[nt] = __builtin_amdgcn_mfma_f32_32x32x16_bf16(afrag, bfrag, acc[nt], 0, 0, 0);
        }
    }

    // ---- stores: col(w)=lane&31 -> each instruction writes 2 full 128B lines
    // (hi=0/1 halves hit adjacent o-rows). NONTEMPORAL: don't evict x from L3.
    #pragma unroll
    for (int nt = 0; nt < 4; ++nt) {
        const int o_base = nt * 32 + hi * 4;
        #pragma unroll
        for (int r = 0; r < 16; ++r) {
            const int o = o_base + (r & 3) + 8 * (r >> 2);
            __builtin_nontemporal_store(acc[nt][r], op + (size_t)o * 16384);
        }
    }
}

extern "C" void kernel_launch(void* const* d_in, const int* in_sizes, int n_in,
                              void* d_out, int out_size, void* d_ws, size_t ws_size,
                              hipStream_t stream) {
    const float* x      = (const float*)d_in[0];
    const float* alphas = (const float*)d_in[1];
    // betas (d_in[2]) provably unused: contributes only to Im(y), dropped by real().
    float* out = (float*)d_out;

    dim3 grid(512);    // 2 h-rows per block: 512 * 2 = 1024 tiles
    dim3 block(512);
    hipLaunchKernelGGL(kk_freqmix_kernel, grid, block, 0, stream, x, alphas, out);
}